// Round 1
// baseline (940.029 us; speedup 1.0000x reference)
//
#include <hip/hip_runtime.h>
#include <math.h>

#define TT 4096
#define NB 4
#define NROW (NB * TT)   // 16384 rows total
#define HS 64

// ---------------- projection: qkv = x @ [Wq|Wk|Wv] ----------------
// grid 256 blocks x 256 threads; each block: 64 rows x 192 cols, K chunked by 64.
#define PR 64
#define PKC 64
#define PLDX 68   // padded leading dim for x tile (keeps float4 16B alignment, 2-way bank alias only)

__global__ __launch_bounds__(256) void proj_kernel(
    const float* __restrict__ x,
    const float* __restrict__ Wk,
    const float* __restrict__ Wq,
    const float* __restrict__ Wv,
    float* __restrict__ qkv)   // [3][NROW][HS]  (0=Q,1=K,2=V)
{
  __shared__ float xs[PR * PLDX];     // 17.4 KB
  __shared__ float wl[PKC * 192];     // 49.2 KB
  const int t  = threadIdx.x;
  const int tx = t & 15;              // col group: cols tx*12 .. tx*12+11
  const int ty = t >> 4;              // row group: rows ty*4 .. ty*4+3
  const long rb = (long)blockIdx.x * PR;

  float acc[4][12];
#pragma unroll
  for (int i = 0; i < 4; ++i)
#pragma unroll
    for (int j = 0; j < 12; ++j) acc[i][j] = 0.f;

  for (int c0 = 0; c0 < 1024; c0 += PKC) {
    // stage x tile (64x64 floats), coalesced float4
#pragma unroll
    for (int u = 0; u < 4; ++u) {
      int idx = t + u * 256;              // float4 index 0..1023
      int r = idx >> 4, c4 = idx & 15;
      float4 v = *(const float4*)&x[(rb + r) * 1024 + c0 + c4 * 4];
      *(float4*)&xs[r * PLDX + c4 * 4] = v;
    }
    // stage W chunk (64 x 192 combined)
#pragma unroll
    for (int u = 0; u < 12; ++u) {
      int idx = t + u * 256;              // float4 index 0..3071
      int cr = idx / 48;
      int w  = idx % 48;
      int mI = w >> 4;                    // 0=Q,1=K,2=V
      int c4 = w & 15;
      const float* Wm = (mI == 0) ? Wq : ((mI == 1) ? Wk : Wv);
      float4 v = *(const float4*)&Wm[(long)(c0 + cr) * 64 + c4 * 4];
      *(float4*)&wl[cr * 192 + mI * 64 + c4 * 4] = v;
    }
    __syncthreads();

    for (int c = 0; c < PKC; ++c) {
      float xv[4];
#pragma unroll
      for (int i = 0; i < 4; ++i) xv[i] = xs[(ty * 4 + i) * PLDX + c];
      float4 w0 = *(const float4*)&wl[c * 192 + tx * 12];
      float4 w1 = *(const float4*)&wl[c * 192 + tx * 12 + 4];
      float4 w2 = *(const float4*)&wl[c * 192 + tx * 12 + 8];
      float wv[12] = {w0.x, w0.y, w0.z, w0.w, w1.x, w1.y, w1.z, w1.w,
                      w2.x, w2.y, w2.z, w2.w};
#pragma unroll
      for (int i = 0; i < 4; ++i)
#pragma unroll
        for (int j = 0; j < 12; ++j)
          acc[i][j] = fmaf(xv[i], wv[j], acc[i][j]);
    }
    __syncthreads();
  }

#pragma unroll
  for (int i = 0; i < 4; ++i) {
    long r = rb + ty * 4 + i;
#pragma unroll
    for (int j = 0; j < 12; ++j) {
      int col = tx * 12 + j;
      int mI = col >> 6;
      int h  = col & 63;
      qkv[((long)mI * NROW + r) * HS + h] = acc[i][j];
    }
  }
}

// ---------------- causal flash attention (fp32) ----------------
// 512 blocks (4 batches x 128 q-tiles of 32 rows), 256 threads.
// 8 lanes per query row, each owns an h-slice of 8.
#define BR 32
#define BC 64

__global__ __launch_bounds__(256) void attn_kernel(
    const float* __restrict__ qkv, float* __restrict__ out)
{
  __shared__ float Kl[BC * HS];   // 16 KB
  __shared__ float Vl[BC * HS];   // 16 KB
  const int t     = threadIdx.x;
  const int lane  = t & 63;
  const int slice = t & 7;        // h-slice owner: h in [slice*8, slice*8+8)
  const int row   = t >> 3;       // 0..31 query row within tile
  const int bi    = blockIdx.x;
  const int b     = bi & 3;
  const int qt    = 127 - (bi >> 2);     // LPT: biggest tiles first
  const int qbase = qt * BR;
  const int qrow  = qbase + row;         // within-batch query index
  const long base = (long)b * TT * HS;
  const float* Qg = qkv + base;
  const float* Kg = qkv + (long)NROW * HS + base;
  const float* Vg = qkv + (long)2 * NROW * HS + base;

  // load q slice, pre-scaled by 1/sqrt(64)
  float4 q0 = *(const float4*)&Qg[(long)qrow * HS + slice * 8];
  float4 q1 = *(const float4*)&Qg[(long)qrow * HS + slice * 8 + 4];
  q0.x *= 0.125f; q0.y *= 0.125f; q0.z *= 0.125f; q0.w *= 0.125f;
  q1.x *= 0.125f; q1.y *= 0.125f; q1.z *= 0.125f; q1.w *= 0.125f;

  float acc[8];
#pragma unroll
  for (int i = 0; i < 8; ++i) acc[i] = 0.f;
  float m = -1e30f, l = 0.f;

  const int kend = qbase + BR - 1;   // max key index needed
  for (int kb = 0; kb <= kend; kb += BC) {
    // stage K,V tiles (each 64x64 floats), coalesced float4
#pragma unroll
    for (int u = 0; u < 4; ++u) {
      int idx = t + u * 256;   // float4 idx 0..1023
      ((float4*)Kl)[idx] = ((const float4*)(Kg + (long)kb * HS))[idx];
      ((float4*)Vl)[idx] = ((const float4*)(Vg + (long)kb * HS))[idx];
    }
    __syncthreads();

    // ---- QK^T for this tile; lane owns scores j with (j&7)==slice ----
    float p[8];
#pragma unroll
    for (int j = 0; j < BC; ++j) {
      const float4 ka = *(const float4*)&Kl[j * HS + slice * 8];
      const float4 kb4 = *(const float4*)&Kl[j * HS + slice * 8 + 4];
      float s = q0.x * ka.x;
      s = fmaf(q0.y, ka.y, s);
      s = fmaf(q0.z, ka.z, s);
      s = fmaf(q0.w, ka.w, s);
      s = fmaf(q1.x, kb4.x, s);
      s = fmaf(q1.y, kb4.y, s);
      s = fmaf(q1.z, kb4.z, s);
      s = fmaf(q1.w, kb4.w, s);
      s += __shfl_xor(s, 1);
      s += __shfl_xor(s, 2);
      s += __shfl_xor(s, 4);
      s = (kb + j > qrow) ? -1e30f : s;   // causal mask
      if ((j & 7) == slice) p[j >> 3] = s;
    }

    // ---- online softmax update ----
    float mt = p[0];
#pragma unroll
    for (int k = 1; k < 8; ++k) mt = fmaxf(mt, p[k]);
    mt = fmaxf(mt, __shfl_xor(mt, 1));
    mt = fmaxf(mt, __shfl_xor(mt, 2));
    mt = fmaxf(mt, __shfl_xor(mt, 4));
    const float mn = fmaxf(m, mt);
    const float corr = __expf(m - mn);
    float ls = 0.f;
#pragma unroll
    for (int k = 0; k < 8; ++k) {
      p[k] = __expf(p[k] - mn);
      ls += p[k];
    }
    ls += __shfl_xor(ls, 1);
    ls += __shfl_xor(ls, 2);
    ls += __shfl_xor(ls, 4);
    l = l * corr + ls;
    m = mn;
#pragma unroll
    for (int i = 0; i < 8; ++i) acc[i] *= corr;

    // ---- PV ----
#pragma unroll
    for (int j = 0; j < BC; ++j) {
      float pj = __shfl(p[j >> 3], (lane & ~7) | (j & 7), 64);
      const float4 va = *(const float4*)&Vl[j * HS + slice * 8];
      const float4 vb = *(const float4*)&Vl[j * HS + slice * 8 + 4];
      acc[0] = fmaf(pj, va.x, acc[0]);
      acc[1] = fmaf(pj, va.y, acc[1]);
      acc[2] = fmaf(pj, va.z, acc[2]);
      acc[3] = fmaf(pj, va.w, acc[3]);
      acc[4] = fmaf(pj, vb.x, acc[4]);
      acc[5] = fmaf(pj, vb.y, acc[5]);
      acc[6] = fmaf(pj, vb.z, acc[6]);
      acc[7] = fmaf(pj, vb.w, acc[7]);
    }
    __syncthreads();
  }

  const float inv = 1.f / l;
  float4 o0 = make_float4(acc[0] * inv, acc[1] * inv, acc[2] * inv, acc[3] * inv);
  float4 o1 = make_float4(acc[4] * inv, acc[5] * inv, acc[6] * inv, acc[7] * inv);
  *(float4*)&out[((long)b * TT + qrow) * HS + slice * 8] = o0;
  *(float4*)&out[((long)b * TT + qrow) * HS + slice * 8 + 4] = o1;
}

extern "C" void kernel_launch(void* const* d_in, const int* in_sizes, int n_in,
                              void* d_out, int out_size, void* d_ws, size_t ws_size,
                              hipStream_t stream) {
  const float* x  = (const float*)d_in[0];
  const float* Wk = (const float*)d_in[1];
  const float* Wq = (const float*)d_in[2];
  const float* Wv = (const float*)d_in[3];
  float* out = (float*)d_out;
  float* qkv = (float*)d_ws;   // needs 3*16384*64*4 = 12.6 MB of workspace

  proj_kernel<<<NROW / PR, 256, 0, stream>>>(x, Wk, Wq, Wv, qkv);
  attn_kernel<<<NB * (TT / BR), 256, 0, stream>>>(qkv, out);
}

// Round 3
// 414.789 us; speedup vs baseline: 2.2663x; 2.2663x over previous
//
#include <hip/hip_runtime.h>

typedef short v8s __attribute__((ext_vector_type(8)));
typedef float f32x4 __attribute__((ext_vector_type(4)));

#define TT 4096
#define NB 4
#define NROW (NB * TT)
#define LOG2E 1.44269504088896f

#define MFMA(A, B, C) __builtin_amdgcn_mfma_f32_16x16x32_bf16((A), (B), (C), 0, 0, 0)

__device__ __forceinline__ unsigned short bfh(float x) {
  union { float f; unsigned u; } c; c.f = x;
  unsigned r = c.u + 0x7fffu + ((c.u >> 16) & 1u);
  return (unsigned short)(r >> 16);
}
__device__ __forceinline__ float bff(unsigned short h) {
  union { unsigned u; float f; } c; c.u = ((unsigned)h) << 16; return c.f;
}

// ---------- prep: W (fp32 [1024][64] x3) -> WT_hi/WT_lo bf16 [192][1024] ----------
// row = mat*64 + h; mat 0=Q (pre-scaled by 0.125*log2e), 1=K, 2=V.
__global__ __launch_bounds__(256) void prep_w(
    const float* __restrict__ Wk, const float* __restrict__ Wq, const float* __restrict__ Wv,
    unsigned short* __restrict__ WTh, unsigned short* __restrict__ WTl) {
  const int row = blockIdx.x;          // 0..191
  const int mI = row >> 6, h = row & 63;
  const float* src = (mI == 0) ? Wq : ((mI == 1) ? Wk : Wv);
  const float scale = (mI == 0) ? 0.125f * LOG2E : 1.0f;
  for (int c = threadIdx.x; c < 1024; c += 256) {
    float v = src[c * 64 + h] * scale;
    unsigned short hi = bfh(v);
    WTh[row * 1024 + c] = hi;
    WTl[row * 1024 + c] = bfh(v - bff(hi));
  }
}

// ---------- projection via MFMA, split-bf16 (x = xh+xl, w = wh+wl; drop xl*wl) ----------
// 256 blocks x 256 thr; block = 64 rows; wave = 16 rows x 192 cols.
__global__ __launch_bounds__(256) void proj_kernel(
    const float* __restrict__ x,
    const unsigned short* __restrict__ WTh, const unsigned short* __restrict__ WTl,
    unsigned short* __restrict__ Qh, unsigned short* __restrict__ Ql,
    unsigned short* __restrict__ Kh, unsigned short* __restrict__ Kl,
    unsigned short* __restrict__ VTh, unsigned short* __restrict__ VTl) {
  const int t = threadIdx.x;
  const int lane = t & 63;
  const int wv = t >> 6;
  const int g = lane >> 4;
  const int q15 = lane & 15;
  const int rb = blockIdx.x * 64 + wv * 16;
  const int rowA = rb + q15;

  f32x4 acc[12] = {};

  for (int ck = 0; ck < 32; ++ck) {
    const int c0 = ck * 32;
    f32x4 f0 = *(const f32x4*)&x[rowA * 1024 + c0 + g * 8];
    f32x4 f1 = *(const f32x4*)&x[rowA * 1024 + c0 + g * 8 + 4];
    v8s xh, xl;
#pragma unroll
    for (int i = 0; i < 8; ++i) {
      float v = (i < 4) ? f0[i] : f1[i - 4];
      unsigned short hh = bfh(v);
      xh[i] = (short)hh;
      xl[i] = (short)bfh(v - bff(hh));
    }
#pragma unroll
    for (int ct = 0; ct < 12; ++ct) {
      const int wrow = ct * 16 + q15;
      v8s wh = *(const v8s*)&WTh[wrow * 1024 + c0 + g * 8];
      v8s wl = *(const v8s*)&WTl[wrow * 1024 + c0 + g * 8];
      acc[ct] = MFMA(xl, wh, acc[ct]);
      acc[ct] = MFMA(xh, wl, acc[ct]);
      acc[ct] = MFMA(xh, wh, acc[ct]);
    }
  }

  // epilogue: split to hi/lo bf16; Q,K row-major [row][64]; V transposed [b][h][t]
#pragma unroll
  for (int ct = 0; ct < 12; ++ct) {
    const int mI = ct >> 2;
    const int h = (ct & 3) * 16 + q15;
#pragma unroll
    for (int r = 0; r < 4; ++r) {
      const int row = rb + g * 4 + r;
      float v = acc[ct][r];
      unsigned short hh = bfh(v);
      unsigned short ll = bfh(v - bff(hh));
      if (mI == 0)      { Qh[row * 64 + h] = hh; Ql[row * 64 + h] = ll; }
      else if (mI == 1) { Kh[row * 64 + h] = hh; Kl[row * 64 + h] = ll; }
      else {
        const int b = row >> 12, tb = row & 4095;
        VTh[(b * 64 + h) * 4096 + tb] = hh;
        VTl[(b * 64 + h) * 4096 + tb] = ll;
      }
    }
  }
}

// ---------- causal flash attention, MFMA, no LDS ----------
// 1024 blocks x 64 thr (1 wave = 16 query rows), LPT order.
// Swapped QK^T: S^T = K*Q -> D[key_slot][q]; key permutation folded into K loads so
// S^T frags are exactly the PV B-operand (P^T) layout. PV: out^T = V^T * P^T.
__global__ __launch_bounds__(64) void attn_kernel(
    const unsigned short* __restrict__ Qh, const unsigned short* __restrict__ Ql,
    const unsigned short* __restrict__ Kh, const unsigned short* __restrict__ Kl,
    const unsigned short* __restrict__ VTh, const unsigned short* __restrict__ VTl,
    float* __restrict__ out) {
  const int lane = threadIdx.x;
  const int g = lane >> 4;
  const int q15 = lane & 15;
  const int bid = blockIdx.x;
  const int b = bid & 3;
  const int qt = 255 - (bid >> 2);       // LPT: longest first
  const int qbase = qt * 16;
  const int bbase = b * TT;
  const int qg = qbase + q15;
  const int nfull = qbase >> 5;

  // Q fragments (B-operand): lane holds Q[q15][chunk*32 + g*8 + i]
  const int qrow = (bbase + qbase + q15) * 64;
  const v8s qh0 = *(const v8s*)&Qh[qrow + g * 8];
  const v8s qh1 = *(const v8s*)&Qh[qrow + 32 + g * 8];
  const v8s ql0 = *(const v8s*)&Ql[qrow + g * 8];
  const v8s ql1 = *(const v8s*)&Ql[qrow + 32 + g * 8];

  f32x4 o[4] = {};
  float m = -1e30f, l = 0.f;

  // permuted key row base: key = kb + 8*(rho>>2) + 4*f + (rho&3), rho = q15 (A-row)
  const int kperm = bbase + 8 * (q15 >> 2) + (q15 & 3);
  const int vrow = b * 64;

  v8s kh_a[2][2], kl_a[2][2], vh_a[4], vl_a[4];
  v8s kh_b[2][2], kl_b[2][2], vh_b[4], vl_b[4];

  auto loadK = [&](int KB, v8s (&KH)[2][2], v8s (&KL)[2][2]) {
#pragma unroll
    for (int f = 0; f < 2; ++f)
#pragma unroll
      for (int ch = 0; ch < 2; ++ch) {
        const int off = (kperm + KB + 4 * f) * 64 + ch * 32 + g * 8;
        KH[f][ch] = *(const v8s*)&Kh[off];
        KL[f][ch] = *(const v8s*)&Kl[off];
      }
  };
  auto loadV = [&](int KB, v8s (&VH)[4], v8s (&VL)[4]) {
#pragma unroll
    for (int ht = 0; ht < 4; ++ht) {
      const int off = (vrow + ht * 16 + q15) * 4096 + KB + g * 8;
      VH[ht] = *(const v8s*)&VTh[off];
      VL[ht] = *(const v8s*)&VTl[off];
    }
  };

  auto body = [&](v8s (&KH)[2][2], v8s (&KL)[2][2], v8s (&VH)[4], v8s (&VL)[4], int it_) {
    const int kbase = it_ * 32;
    f32x4 s0 = {}, s1 = {};
    s0 = MFMA(KL[0][0], qh0, s0);
    s0 = MFMA(KL[0][1], qh1, s0);
    s0 = MFMA(KH[0][0], ql0, s0);
    s0 = MFMA(KH[0][1], ql1, s0);
    s0 = MFMA(KH[0][0], qh0, s0);
    s0 = MFMA(KH[0][1], qh1, s0);
    s1 = MFMA(KL[1][0], qh0, s1);
    s1 = MFMA(KL[1][1], qh1, s1);
    s1 = MFMA(KH[1][0], ql0, s1);
    s1 = MFMA(KH[1][1], ql1, s1);
    s1 = MFMA(KH[1][0], qh0, s1);
    s1 = MFMA(KH[1][1], qh1, s1);

    if (it_ == nfull) {  // causal mask, permuted key ids
      const int kk = kbase + 8 * g;
#pragma unroll
      for (int r = 0; r < 4; ++r) {
        if (kk + r > qg)     s0[r] = -1e30f;
        if (kk + 4 + r > qg) s1[r] = -1e30f;
      }
    }

    float pmax = fmaxf(fmaxf(fmaxf(s0[0], s0[1]), fmaxf(s0[2], s0[3])),
                       fmaxf(fmaxf(s1[0], s1[1]), fmaxf(s1[2], s1[3])));
    pmax = fmaxf(pmax, __shfl_xor(pmax, 16));
    pmax = fmaxf(pmax, __shfl_xor(pmax, 32));
    if (!__all(pmax <= m + 8.0f)) {      // defer-max (scores are log2-scaled)
      const float mn = fmaxf(m, pmax);
      const float corr = __builtin_amdgcn_exp2f(m - mn);
      l *= corr;
#pragma unroll
      for (int ht = 0; ht < 4; ++ht)
#pragma unroll
        for (int j = 0; j < 4; ++j) o[ht][j] *= corr;
      m = mn;
    }
    float ls = 0.f;
#pragma unroll
    for (int r = 0; r < 4; ++r) { s0[r] = __builtin_amdgcn_exp2f(s0[r] - m); ls += s0[r]; }
#pragma unroll
    for (int r = 0; r < 4; ++r) { s1[r] = __builtin_amdgcn_exp2f(s1[r] - m); ls += s1[r]; }
    ls += __shfl_xor(ls, 16);
    ls += __shfl_xor(ls, 32);
    l += ls;

    v8s ph, pl;
#pragma unroll
    for (int r = 0; r < 4; ++r) {
      unsigned short h0 = bfh(s0[r]);
      ph[r] = (short)h0;
      pl[r] = (short)bfh(s0[r] - bff(h0));
      unsigned short h1 = bfh(s1[r]);
      ph[4 + r] = (short)h1;
      pl[4 + r] = (short)bfh(s1[r] - bff(h1));
    }
#pragma unroll
    for (int ht = 0; ht < 4; ++ht) {
      o[ht] = MFMA(VL[ht], ph, o[ht]);
      o[ht] = MFMA(VH[ht], pl, o[ht]);
      o[ht] = MFMA(VH[ht], ph, o[ht]);
    }
  };

  loadK(0, kh_a, kl_a);
  loadV(0, vh_a, vl_a);
  int it = 0;
  for (;;) {
    if (it < nfull) { loadK((it + 1) * 32, kh_b, kl_b); loadV((it + 1) * 32, vh_b, vl_b); }
    body(kh_a, kl_a, vh_a, vl_a, it);
    if (it == nfull) break;
    ++it;
    if (it < nfull) { loadK((it + 1) * 32, kh_a, kl_a); loadV((it + 1) * 32, vh_a, vl_a); }
    body(kh_b, kl_b, vh_b, vl_b, it);
    if (it == nfull) break;
    ++it;
  }

  const float inv = 1.0f / l;
  const int orow = (bbase + qbase + q15) * 64;
#pragma unroll
  for (int ht = 0; ht < 4; ++ht) {
    f32x4 v;
#pragma unroll
    for (int j = 0; j < 4; ++j) v[j] = o[ht][j] * inv;
    *(f32x4*)&out[orow + ht * 16 + g * 4] = v;
  }
}

extern "C" void kernel_launch(void* const* d_in, const int* in_sizes, int n_in,
                              void* d_out, int out_size, void* d_ws, size_t ws_size,
                              hipStream_t stream) {
  const float* x  = (const float*)d_in[0];
  const float* Wk = (const float*)d_in[1];
  const float* Wq = (const float*)d_in[2];
  const float* Wv = (const float*)d_in[3];
  float* out = (float*)d_out;

  // ws: 6 arrays x 1M bf16 = 12.58 MB (== proven R1 footprint)
  unsigned short* Qh  = (unsigned short*)d_ws;
  unsigned short* Ql  = Qh  + NROW * 64;
  unsigned short* Kh  = Ql  + NROW * 64;
  unsigned short* Kl  = Kh  + NROW * 64;
  unsigned short* VTh = Kl  + NROW * 64;
  unsigned short* VTl = VTh + NROW * 64;

  // W^T scratch lives in d_out (consumed by proj before attn overwrites d_out)
  unsigned short* WTh = (unsigned short*)d_out;
  unsigned short* WTl = WTh + 192 * 1024;

  prep_w<<<192, 256, 0, stream>>>(Wk, Wq, Wv, WTh, WTl);
  proj_kernel<<<256, 256, 0, stream>>>(x, WTh, WTl, Qh, Ql, Kh, Kl, VTh, VTl);
  attn_kernel<<<1024, 64, 0, stream>>>(Qh, Ql, Kh, Kl, VTh, VTl, out);
}

// Round 4
// 336.224 us; speedup vs baseline: 2.7958x; 1.2337x over previous
//
#include <hip/hip_runtime.h>

typedef short v8s __attribute__((ext_vector_type(8)));
typedef float f32x4 __attribute__((ext_vector_type(4)));

#define TT 4096
#define NB 4
#define NROW (NB * TT)
#define LOG2E 1.44269504088896f

#define MFMA(A, B, C) __builtin_amdgcn_mfma_f32_16x16x32_bf16((A), (B), (C), 0, 0, 0)

__device__ __forceinline__ unsigned short bfh(float x) {
  union { float f; unsigned u; } c; c.f = x;
  unsigned r = c.u + 0x7fffu + ((c.u >> 16) & 1u);
  return (unsigned short)(r >> 16);
}
__device__ __forceinline__ float bff(unsigned short h) {
  union { unsigned u; float f; } c; c.u = ((unsigned)h) << 16; return c.f;
}

// ---------- prep: W (fp32 [1024][64] x3) -> WT_hi/WT_lo bf16 [192][1024] ----------
__global__ __launch_bounds__(256) void prep_w(
    const float* __restrict__ Wk, const float* __restrict__ Wq, const float* __restrict__ Wv,
    unsigned short* __restrict__ WTh, unsigned short* __restrict__ WTl) {
  const int row = blockIdx.x;          // 0..191
  const int mI = row >> 6, h = row & 63;
  const float* src = (mI == 0) ? Wq : ((mI == 1) ? Wk : Wv);
  const float scale = (mI == 0) ? 0.125f * LOG2E : 1.0f;
  for (int c = threadIdx.x; c < 1024; c += 256) {
    float v = src[c * 64 + h] * scale;
    unsigned short hi = bfh(v);
    WTh[row * 1024 + c] = hi;
    WTl[row * 1024 + c] = bfh(v - bff(hi));
  }
}

// ---------- projection via MFMA, split-bf16 ----------
// 768 blocks x 256 thr; wave tile = 16 rows x 64 cols (one matrix). 3072 waves (3/SIMD).
__global__ __launch_bounds__(256, 4) void proj_kernel(
    const float* __restrict__ x,
    const unsigned short* __restrict__ WTh, const unsigned short* __restrict__ WTl,
    unsigned short* __restrict__ Qh, unsigned short* __restrict__ Ql,
    unsigned short* __restrict__ Kh, unsigned short* __restrict__ Kl,
    unsigned short* __restrict__ VTh, unsigned short* __restrict__ VTl) {
  const int t = threadIdx.x;
  const int lane = t & 63;
  const int wv = t >> 6;
  const int g = lane >> 4;
  const int q15 = lane & 15;
  const int bid = blockIdx.x;
  const int mat = bid >> 8;                    // 0=Q, 1=K, 2=V
  const int rb = (bid & 255) * 64 + wv * 16;
  const int rowA = rb + q15;

  const unsigned short* WhB = WTh + mat * 64 * 1024;
  const unsigned short* WlB = WTl + mat * 64 * 1024;

  f32x4 acc[4] = {};

  for (int ck = 0; ck < 32; ++ck) {
    const int c0 = ck * 32;
    f32x4 f0 = *(const f32x4*)&x[(long)rowA * 1024 + c0 + g * 8];
    f32x4 f1 = *(const f32x4*)&x[(long)rowA * 1024 + c0 + g * 8 + 4];
    v8s xh, xl;
#pragma unroll
    for (int i = 0; i < 8; ++i) {
      float v = (i < 4) ? f0[i] : f1[i - 4];
      unsigned short hh = bfh(v);
      xh[i] = (short)hh;
      xl[i] = (short)bfh(v - bff(hh));
    }
#pragma unroll
    for (int ct = 0; ct < 4; ++ct) {
      const int wrow = ct * 16 + q15;
      v8s wh = *(const v8s*)&WhB[wrow * 1024 + c0 + g * 8];
      v8s wl = *(const v8s*)&WlB[wrow * 1024 + c0 + g * 8];
      acc[ct] = MFMA(xl, wh, acc[ct]);
      acc[ct] = MFMA(xh, wl, acc[ct]);
      acc[ct] = MFMA(xh, wh, acc[ct]);
    }
  }

#pragma unroll
  for (int ct = 0; ct < 4; ++ct) {
    const int h = ct * 16 + q15;
#pragma unroll
    for (int r = 0; r < 4; ++r) {
      const int row = rb + g * 4 + r;
      float v = acc[ct][r];
      unsigned short hh = bfh(v);
      unsigned short ll = bfh(v - bff(hh));
      if (mat == 0)      { Qh[row * 64 + h] = hh; Ql[row * 64 + h] = ll; }
      else if (mat == 1) { Kh[row * 64 + h] = hh; Kl[row * 64 + h] = ll; }
      else {
        const int b = row >> 12, tb = row & 4095;
        VTh[(b * 64 + h) * 4096 + tb] = hh;
        VTl[(b * 64 + h) * 4096 + tb] = ll;
      }
    }
  }
}

// ---------- causal flash attention, MFMA, 4-way intra-block split-K ----------
// 1024 blocks x 256 thr (4 waves). Wave w handles chunks c = w, w+4, ... (32 keys each)
// with private online-softmax state; LDS combine at the end. 4096 waves total.
__global__ __launch_bounds__(256, 3) void attn_kernel(
    const unsigned short* __restrict__ Qh, const unsigned short* __restrict__ Ql,
    const unsigned short* __restrict__ Kh, const unsigned short* __restrict__ Kl,
    const unsigned short* __restrict__ VTh, const unsigned short* __restrict__ VTl,
    float* __restrict__ out) {
  const int t = threadIdx.x;
  const int lane = t & 63;
  const int wv = t >> 6;
  const int g = lane >> 4;
  const int q15 = lane & 15;
  const int bid = blockIdx.x;
  const int b = bid & 3;
  const int qt = 255 - (bid >> 2);       // LPT: longest first
  const int qbase = qt * 16;
  const int bbase = b * TT;
  const int qg = qbase + q15;
  const int nfull = qbase >> 5;          // last (diagonal) chunk index

  __shared__ float red_m[4][16];
  __shared__ float red_l[4][16];
  __shared__ float osum[16][65];

  // Q fragments (B-operand): lane holds Q[q15][chunk*32 + g*8 + i]
  const int qrow = (bbase + qbase + q15) * 64;
  const v8s qh0 = *(const v8s*)&Qh[qrow + g * 8];
  const v8s qh1 = *(const v8s*)&Qh[qrow + 32 + g * 8];
  const v8s ql0 = *(const v8s*)&Ql[qrow + g * 8];
  const v8s ql1 = *(const v8s*)&Ql[qrow + 32 + g * 8];

  f32x4 o[4] = {};
  float m = -1e30f, l = 0.f;

  // permuted key row base: key = KB + 8*(rho>>2) + 4*f + (rho&3), rho = q15 (A-row)
  const int kperm = bbase + 8 * (q15 >> 2) + (q15 & 3);
  const int vrow = b * 64;

  v8s KH[2][2], KL[2][2], VH[4], VL[4];

  auto loadK = [&](int KB) {
#pragma unroll
    for (int f = 0; f < 2; ++f)
#pragma unroll
      for (int ch = 0; ch < 2; ++ch) {
        const int off = (kperm + KB + 4 * f) * 64 + ch * 32 + g * 8;
        KH[f][ch] = *(const v8s*)&Kh[off];
        KL[f][ch] = *(const v8s*)&Kl[off];
      }
  };
  auto loadV = [&](int KB) {
#pragma unroll
    for (int ht = 0; ht < 4; ++ht) {
      const int off = (vrow + ht * 16 + q15) * 4096 + KB + g * 8;
      VH[ht] = *(const v8s*)&VTh[off];
      VL[ht] = *(const v8s*)&VTl[off];
    }
  };

  if (wv <= nfull) {
    int c = wv;
    loadK(c * 32);
    loadV(c * 32);
    for (;;) {
      // ---- QK^T (S^T frags == PV B-operand layout via kperm) ----
      f32x4 s0 = {}, s1 = {};
      s0 = MFMA(KL[0][0], qh0, s0);
      s0 = MFMA(KL[0][1], qh1, s0);
      s0 = MFMA(KH[0][0], ql0, s0);
      s0 = MFMA(KH[0][1], ql1, s0);
      s0 = MFMA(KH[0][0], qh0, s0);
      s0 = MFMA(KH[0][1], qh1, s0);
      s1 = MFMA(KL[1][0], qh0, s1);
      s1 = MFMA(KL[1][1], qh1, s1);
      s1 = MFMA(KH[1][0], ql0, s1);
      s1 = MFMA(KH[1][1], ql1, s1);
      s1 = MFMA(KH[1][0], qh0, s1);
      s1 = MFMA(KH[1][1], qh1, s1);

      const int nxt = c + 4;
      if (nxt <= nfull) loadK(nxt * 32);   // pipeline: K consumed above

      if (c == nfull) {                    // causal mask (permuted key ids)
        const int kk = c * 32 + 8 * g;
#pragma unroll
        for (int r = 0; r < 4; ++r) {
          if (kk + r > qg)     s0[r] = -1e30f;
          if (kk + 4 + r > qg) s1[r] = -1e30f;
        }
      }

      float pmax = fmaxf(fmaxf(fmaxf(s0[0], s0[1]), fmaxf(s0[2], s0[3])),
                         fmaxf(fmaxf(s1[0], s1[1]), fmaxf(s1[2], s1[3])));
      pmax = fmaxf(pmax, __shfl_xor(pmax, 16));
      pmax = fmaxf(pmax, __shfl_xor(pmax, 32));
      if (!__all(pmax <= m + 8.0f)) {      // defer-max (log2 domain)
        const float mn = fmaxf(m, pmax);
        const float corr = __builtin_amdgcn_exp2f(m - mn);
        l *= corr;
#pragma unroll
        for (int ht = 0; ht < 4; ++ht)
#pragma unroll
          for (int j = 0; j < 4; ++j) o[ht][j] *= corr;
        m = mn;
      }
      float ls = 0.f;
#pragma unroll
      for (int r = 0; r < 4; ++r) { s0[r] = __builtin_amdgcn_exp2f(s0[r] - m); ls += s0[r]; }
#pragma unroll
      for (int r = 0; r < 4; ++r) { s1[r] = __builtin_amdgcn_exp2f(s1[r] - m); ls += s1[r]; }
      ls += __shfl_xor(ls, 16);
      ls += __shfl_xor(ls, 32);
      l += ls;

      v8s ph, pl;
#pragma unroll
      for (int r = 0; r < 4; ++r) {
        unsigned short h0 = bfh(s0[r]);
        ph[r] = (short)h0;
        pl[r] = (short)bfh(s0[r] - bff(h0));
        unsigned short h1 = bfh(s1[r]);
        ph[4 + r] = (short)h1;
        pl[4 + r] = (short)bfh(s1[r] - bff(h1));
      }
#pragma unroll
      for (int ht = 0; ht < 4; ++ht) {
        o[ht] = MFMA(VL[ht], ph, o[ht]);
        o[ht] = MFMA(VH[ht], pl, o[ht]);
        o[ht] = MFMA(VH[ht], ph, o[ht]);
      }
      if (nxt > nfull) break;
      loadV(nxt * 32);                     // pipeline: V consumed above
      c = nxt;
    }
  }

  // ---- cross-wave combine ----
  if (lane < 16) { red_m[wv][q15] = m; red_l[wv][q15] = l; }
  for (int i = t; i < 16 * 65; i += 256) ((float*)osum)[i] = 0.f;
  __syncthreads();

  const float gm = fmaxf(fmaxf(red_m[0][q15], red_m[1][q15]),
                         fmaxf(red_m[2][q15], red_m[3][q15]));
  const float myscale = __builtin_amdgcn_exp2f(m - gm);

#pragma unroll
  for (int w = 0; w < 4; ++w) {
    if (wv == w) {
#pragma unroll
      for (int ht = 0; ht < 4; ++ht)
#pragma unroll
        for (int j = 0; j < 4; ++j)
          osum[q15][ht * 16 + g * 4 + j] += o[ht][j] * myscale;
    }
    __syncthreads();
  }

  // ---- store ----
  const int q = t >> 4;
  const int h0 = (t & 15) * 4;
  const float gmq = fmaxf(fmaxf(red_m[0][q], red_m[1][q]),
                          fmaxf(red_m[2][q], red_m[3][q]));
  float lt = 0.f;
#pragma unroll
  for (int w = 0; w < 4; ++w)
    lt += red_l[w][q] * __builtin_amdgcn_exp2f(red_m[w][q] - gmq);
  const float inv = 1.0f / lt;
  f32x4 v;
#pragma unroll
  for (int j = 0; j < 4; ++j) v[j] = osum[q][h0 + j] * inv;
  *(f32x4*)&out[(long)(bbase + qbase + q) * 64 + h0] = v;
}

extern "C" void kernel_launch(void* const* d_in, const int* in_sizes, int n_in,
                              void* d_out, int out_size, void* d_ws, size_t ws_size,
                              hipStream_t stream) {
  const float* x  = (const float*)d_in[0];
  const float* Wk = (const float*)d_in[1];
  const float* Wq = (const float*)d_in[2];
  const float* Wv = (const float*)d_in[3];
  float* out = (float*)d_out;

  unsigned short* Qh  = (unsigned short*)d_ws;
  unsigned short* Ql  = Qh  + NROW * 64;
  unsigned short* Kh  = Ql  + NROW * 64;
  unsigned short* Kl  = Kh  + NROW * 64;
  unsigned short* VTh = Kl  + NROW * 64;
  unsigned short* VTl = VTh + NROW * 64;

  // W^T scratch lives in d_out (consumed by proj; attn fully overwrites d_out)
  unsigned short* WTh = (unsigned short*)d_out;
  unsigned short* WTl = WTh + 192 * 1024;

  prep_w<<<192, 256, 0, stream>>>(Wk, Wq, Wv, WTh, WTl);
  proj_kernel<<<768, 256, 0, stream>>>(x, WTh, WTl, Qh, Ql, Kh, Kl, VTh, VTl);
  attn_kernel<<<1024, 256, 0, stream>>>(Qh, Ql, Kh, Kl, VTh, VTl, out);
}

// Round 5
// 231.545 us; speedup vs baseline: 4.0598x; 1.4521x over previous
//
#include <hip/hip_runtime.h>

typedef _Float16 v8h __attribute__((ext_vector_type(8)));
typedef _Float16 v4h __attribute__((ext_vector_type(4)));
typedef float f32x4 __attribute__((ext_vector_type(4)));

#define TT 4096
#define NB 4
#define NROW (NB * TT)
#define LOG2E 1.44269504088896f

#define MFMA16(A, B, C) __builtin_amdgcn_mfma_f32_16x16x32_f16((A), (B), (C), 0, 0, 0)

// ---------- prep: W (fp32 [1024][64] x3) -> WT f16 [192][1024] ----------
// row = mat*64 + h; mat 0=Q (pre-scaled by 0.125*log2e), 1=K, 2=V.
__global__ __launch_bounds__(256) void prep_w(
    const float* __restrict__ Wk, const float* __restrict__ Wq, const float* __restrict__ Wv,
    _Float16* __restrict__ WT) {
  const int row = blockIdx.x;          // 0..191
  const int mI = row >> 6, h = row & 63;
  const float* src = (mI == 0) ? Wq : ((mI == 1) ? Wk : Wv);
  const float scale = (mI == 0) ? 0.125f * LOG2E : 1.0f;
  for (int c = threadIdx.x; c < 1024; c += 256)
    WT[row * 1024 + c] = (_Float16)(src[c * 64 + h] * scale);
}

// ---------- projection via f16 MFMA ----------
// 768 blocks x 256 thr; wave tile = 16 rows x 64 cols (one matrix); K-step 64.
__global__ __launch_bounds__(256, 4) void proj_kernel(
    const float* __restrict__ x, const _Float16* __restrict__ WT,
    _Float16* __restrict__ Qf, _Float16* __restrict__ Kf, _Float16* __restrict__ VTf) {
  const int t = threadIdx.x;
  const int lane = t & 63;
  const int wv = t >> 6;
  const int g = lane >> 4;
  const int q15 = lane & 15;
  const int bid = blockIdx.x;
  const int mat = bid >> 8;                    // 0=Q, 1=K, 2=V
  const int rb = (bid & 255) * 64 + wv * 16;
  const int rowA = rb + q15;

  const _Float16* WB = WT + mat * 64 * 1024;

  f32x4 acc[4] = {};

  for (int c0 = 0; c0 < 1024; c0 += 64) {
    const long xb0 = (long)rowA * 1024 + c0 + g * 8;
    f32x4 fa0 = *(const f32x4*)&x[xb0];
    f32x4 fa1 = *(const f32x4*)&x[xb0 + 4];
    f32x4 fb0 = *(const f32x4*)&x[xb0 + 32];
    f32x4 fb1 = *(const f32x4*)&x[xb0 + 36];
    v8h xa, xb;
#pragma unroll
    for (int i = 0; i < 4; ++i) {
      xa[i] = (_Float16)fa0[i];
      xa[4 + i] = (_Float16)fa1[i];
      xb[i] = (_Float16)fb0[i];
      xb[4 + i] = (_Float16)fb1[i];
    }
    v8h wa[4], wb[4];
#pragma unroll
    for (int ct = 0; ct < 4; ++ct) {
      const int wrow = (ct * 16 + q15) * 1024 + c0 + g * 8;
      wa[ct] = *(const v8h*)&WB[wrow];
      wb[ct] = *(const v8h*)&WB[wrow + 32];
    }
#pragma unroll
    for (int ct = 0; ct < 4; ++ct) {
      acc[ct] = MFMA16(xa, wa[ct], acc[ct]);
      acc[ct] = MFMA16(xb, wb[ct], acc[ct]);
    }
  }

#pragma unroll
  for (int ct = 0; ct < 4; ++ct) {
    const int h = ct * 16 + q15;
    if (mat == 2) {
      // V transposed [b][h][t]; 4 consecutive t per lane -> packed 8B store
      const int row0 = rb + g * 4;
      const int b = row0 >> 12, tb = row0 & 4095;
      v4h pv;
#pragma unroll
      for (int r = 0; r < 4; ++r) pv[r] = (_Float16)acc[ct][r];
      *(v4h*)&VTf[((long)(b * 64 + h)) * 4096 + tb] = pv;
    } else {
      _Float16* dst = (mat == 0) ? Qf : Kf;
#pragma unroll
      for (int r = 0; r < 4; ++r) {
        const int row = rb + g * 4 + r;
        dst[row * 64 + h] = (_Float16)acc[ct][r];
      }
    }
  }
}

// ---------- causal flash attention, f16 MFMA, 4-way intra-block split-K ----------
// 1024 blocks x 256 thr (4 waves). Wave w handles chunks c = w, w+4, ... (32 keys)
// with private online-softmax state; LDS combine at the end.
__global__ __launch_bounds__(256, 4) void attn_kernel(
    const _Float16* __restrict__ Qf, const _Float16* __restrict__ Kf,
    const _Float16* __restrict__ VTf, float* __restrict__ out) {
  const int t = threadIdx.x;
  const int lane = t & 63;
  const int wv = t >> 6;
  const int g = lane >> 4;
  const int q15 = lane & 15;
  const int bid = blockIdx.x;
  const int b = bid & 3;
  const int qt = 255 - (bid >> 2);       // LPT: longest first
  const int qbase = qt * 16;
  const int bbase = b * TT;
  const int qg = qbase + q15;
  const int nfull = qbase >> 5;          // last (diagonal) chunk index

  __shared__ float red_m[4][16];
  __shared__ float red_l[4][16];
  __shared__ float osum[16][65];

  // Q fragments (B-operand): lane holds Q[q15][chunk*32 + g*8 + i]
  const int qrow = (bbase + qbase + q15) * 64;
  const v8h q0 = *(const v8h*)&Qf[qrow + g * 8];
  const v8h q1 = *(const v8h*)&Qf[qrow + 32 + g * 8];

  f32x4 o[4] = {};
  float m = -1e30f, l = 0.f;

  // permuted key row base: key = KB + 8*(rho>>2) + 4*f + (rho&3), rho = q15 (A-row)
  const int kperm = bbase + 8 * (q15 >> 2) + (q15 & 3);
  const int vrow = b * 64;

  v8h KF[2][2], VF[4];

  auto loadK = [&](int KB) {
#pragma unroll
    for (int f = 0; f < 2; ++f)
#pragma unroll
      for (int ch = 0; ch < 2; ++ch)
        KF[f][ch] = *(const v8h*)&Kf[(kperm + KB + 4 * f) * 64 + ch * 32 + g * 8];
  };
  auto loadV = [&](int KB) {
#pragma unroll
    for (int ht = 0; ht < 4; ++ht)
      VF[ht] = *(const v8h*)&VTf[(long)(vrow + ht * 16 + q15) * 4096 + KB + g * 8];
  };

  if (wv <= nfull) {
    int c = wv;
    loadK(c * 32);
    loadV(c * 32);
    for (;;) {
      // ---- QK^T (S^T frags == PV B-operand layout via kperm) ----
      f32x4 s0 = {}, s1 = {};
      __builtin_amdgcn_s_setprio(1);
      s0 = MFMA16(KF[0][0], q0, s0);
      s0 = MFMA16(KF[0][1], q1, s0);
      s1 = MFMA16(KF[1][0], q0, s1);
      s1 = MFMA16(KF[1][1], q1, s1);
      __builtin_amdgcn_s_setprio(0);

      const int nxt = c + 4;
      if (nxt <= nfull) loadK(nxt * 32);   // pipeline: K consumed above

      if (c == nfull) {                    // causal mask (permuted key ids)
        const int kk = c * 32 + 8 * g;
#pragma unroll
        for (int r = 0; r < 4; ++r) {
          if (kk + r > qg)     s0[r] = -1e30f;
          if (kk + 4 + r > qg) s1[r] = -1e30f;
        }
      }

      float pmax = fmaxf(fmaxf(fmaxf(s0[0], s0[1]), fmaxf(s0[2], s0[3])),
                         fmaxf(fmaxf(s1[0], s1[1]), fmaxf(s1[2], s1[3])));
      pmax = fmaxf(pmax, __shfl_xor(pmax, 16));
      pmax = fmaxf(pmax, __shfl_xor(pmax, 32));
      if (!__all(pmax <= m + 8.0f)) {      // defer-max (log2 domain)
        const float mn = fmaxf(m, pmax);
        const float corr = __builtin_amdgcn_exp2f(m - mn);
        l *= corr;
#pragma unroll
        for (int ht = 0; ht < 4; ++ht)
#pragma unroll
          for (int j = 0; j < 4; ++j) o[ht][j] *= corr;
        m = mn;
      }
      float ls = 0.f;
#pragma unroll
      for (int r = 0; r < 4; ++r) { s0[r] = __builtin_amdgcn_exp2f(s0[r] - m); ls += s0[r]; }
#pragma unroll
      for (int r = 0; r < 4; ++r) { s1[r] = __builtin_amdgcn_exp2f(s1[r] - m); ls += s1[r]; }
      ls += __shfl_xor(ls, 16);
      ls += __shfl_xor(ls, 32);
      l += ls;

      v8h ph;
#pragma unroll
      for (int r = 0; r < 4; ++r) {
        ph[r] = (_Float16)s0[r];
        ph[4 + r] = (_Float16)s1[r];
      }
      __builtin_amdgcn_s_setprio(1);
#pragma unroll
      for (int ht = 0; ht < 4; ++ht) o[ht] = MFMA16(VF[ht], ph, o[ht]);
      __builtin_amdgcn_s_setprio(0);

      if (nxt > nfull) break;
      loadV(nxt * 32);                     // pipeline: V consumed above
      c = nxt;
    }
  }

  // ---- cross-wave combine ----
  if (lane < 16) { red_m[wv][q15] = m; red_l[wv][q15] = l; }
  for (int i = t; i < 16 * 65; i += 256) ((float*)osum)[i] = 0.f;
  __syncthreads();

  const float gm = fmaxf(fmaxf(red_m[0][q15], red_m[1][q15]),
                         fmaxf(red_m[2][q15], red_m[3][q15]));
  const float myscale = __builtin_amdgcn_exp2f(m - gm);

#pragma unroll
  for (int w = 0; w < 4; ++w) {
    if (wv == w) {
#pragma unroll
      for (int ht = 0; ht < 4; ++ht)
#pragma unroll
        for (int j = 0; j < 4; ++j)
          osum[q15][ht * 16 + g * 4 + j] += o[ht][j] * myscale;
    }
    __syncthreads();
  }

  // ---- store ----
  const int q = t >> 4;
  const int h0 = (t & 15) * 4;
  const float gmq = fmaxf(fmaxf(red_m[0][q], red_m[1][q]),
                          fmaxf(red_m[2][q], red_m[3][q]));
  float lt = 0.f;
#pragma unroll
  for (int w = 0; w < 4; ++w)
    lt += red_l[w][q] * __builtin_amdgcn_exp2f(red_m[w][q] - gmq);
  const float inv = 1.0f / lt;
  f32x4 v;
#pragma unroll
  for (int j = 0; j < 4; ++j) v[j] = osum[q][h0 + j] * inv;
  *(f32x4*)&out[(long)(bbase + qbase + q) * 64 + h0] = v;
}

extern "C" void kernel_launch(void* const* d_in, const int* in_sizes, int n_in,
                              void* d_out, int out_size, void* d_ws, size_t ws_size,
                              hipStream_t stream) {
  const float* x  = (const float*)d_in[0];
  const float* Wk = (const float*)d_in[1];
  const float* Wq = (const float*)d_in[2];
  const float* Wv = (const float*)d_in[3];
  float* out = (float*)d_out;

  // ws: 3 arrays x 1M f16 = 6.3 MB
  _Float16* Qf  = (_Float16*)d_ws;
  _Float16* Kf  = Qf + NROW * 64;
  _Float16* VTf = Kf + NROW * 64;

  // W^T scratch lives in d_out (consumed by proj; attn fully overwrites d_out)
  _Float16* WT = (_Float16*)d_out;

  prep_w<<<192, 256, 0, stream>>>(Wk, Wq, Wv, WT);
  proj_kernel<<<768, 256, 0, stream>>>(x, WT, Qf, Kf, VTf);
  attn_kernel<<<1024, 256, 0, stream>>>(Qf, Kf, VTf, out);
}